// Round 10
// baseline (195.301 us; speedup 1.0000x reference)
//
#include <hip/hip_runtime.h>

#define LSEQ 1024
#define INDIM 256
#define DM 32
#define PD 64
#define JT 128

typedef float f32x4 __attribute__((ext_vector_type(4)));

__device__ __forceinline__ void fma4(f32x4& a, float s, const f32x4& t) {
  a.x = fmaf(s, t.x, a.x); a.y = fmaf(s, t.y, a.y);
  a.z = fmaf(s, t.z, a.z); a.w = fmaf(s, t.w, a.w);
}

__device__ __forceinline__ void g2l16(const float* g, float* l) {
  __builtin_amdgcn_global_load_lds(
      (__attribute__((address_space(1))) void*)g,
      (__attribute__((address_space(3))) void*)l, 16, 0, 0);
}

// Fused prep, 4 rows per block (unchanged):
template<bool WRT>
__global__ __launch_bounds__(256) void k_prep(const float* __restrict__ seq,
    const float* __restrict__ W1, const float* __restrict__ b1,
    const float* __restrict__ W2, float* __restrict__ sT,
    float* __restrict__ t_out) {
  int i0 = blockIdx.x * 4;
  int tid = threadIdx.x;
  __shared__ float srow[4][INDIM];
  __shared__ float part[4][2][DM];
  __shared__ float si[4][DM];
  ((f32x4*)&srow[0][0])[tid] =
      ((const f32x4*)(seq + (size_t)i0 * INDIM))[tid];
  __syncthreads();
  {
    int c = tid & 31, dseg = (tid >> 5) & 1, il = tid >> 6;
    float a = 0.f;
    #pragma unroll 16
    for (int d = 0; d < 128; ++d)
      a = fmaf(srow[il][dseg * 128 + d], W1[(dseg * 128 + d) * DM + c], a);
    part[il][dseg][c] = a;
  }
  __syncthreads();
  if (tid < 128) {
    int il = tid >> 5, c = tid & 31;
    float a = b1[c] + part[il][0][c] + part[il][1][c];
    si[il][c] = a;
    sT[c * LSEQ + i0 + il] = a;
  }
  __syncthreads();
  if constexpr (WRT) {
    int p = tid & 63, c0 = tid >> 6;
    #pragma unroll
    for (int k = 0; k < 8; ++k) {
      int c = c0 * 8 + k;
      float a0 = 0.f, a1 = 0.f, a2 = 0.f, a3 = 0.f;
      #pragma unroll
      for (int d = 0; d < DM; ++d) {
        float w = W2[(c * DM + d) * PD + p];
        a0 = fmaf(si[0][d], w, a0);
        a1 = fmaf(si[1][d], w, a1);
        a2 = fmaf(si[2][d], w, a2);
        a3 = fmaf(si[3][d], w, a3);
      }
      t_out[((size_t)(i0 + 0) * DM + c) * PD + p] = a0;
      t_out[((size_t)(i0 + 1) * DM + c) * PD + p] = a1;
      t_out[((size_t)(i0 + 2) * DM + c) * PD + p] = a2;
      t_out[((size_t)(i0 + 3) * DM + c) * PD + p] = a3;
    }
  }
}

// out[i][j][p] = sum_c t[i][c][p]*s[j][c] + b2[p] + pair[i][j][p]
// Contiguity remap: lane&15 -> one f32x4 of p (16 lanes span a full 256B row);
// lane>>4 -> row group. Each pair/out wave instruction covers 4 contiguous
// 256B rows (256B runs) instead of 8 scattered 128B segments.
// Thread tile: 8 j (contiguous block of 8 rows) x 4 p. 24 waves/CU.
__global__ __launch_bounds__(256, 6) void k_main(const float* __restrict__ sT,
    const float* __restrict__ tg, const float* __restrict__ b2,
    const float* __restrict__ pair, float* __restrict__ out) {
  __shared__ float t_lds[DM * PD];    // 8 KB
  __shared__ float s_lds[DM][JT];     // 16 KB -> 24 KB total, 6 blocks/CU
  int tid = threadIdx.x;
  int lane = tid & 63, w = tid >> 6;
  // XCD-chunked bijective swizzle (8192 % 8 == 0)
  int bid = ((blockIdx.x & 7) << 10) + (blockIdx.x >> 3);
  int i = bid >> 3;
  int jt = (bid & 7) * JT;
  int pl = lane & 15;                 // p = pl*4 .. pl*4+3
  int g  = lane >> 4;                 // 0..3
  int jbase = jt + w * 32 + g * 8;    // thread rows: jbase + k, k=0..7

  // 1) pair loads straight into accumulators (first thing; land under
  //    staging + barrier)
  size_t ibase = (size_t)i * (LSEQ * PD);
  const f32x4* pp = (const f32x4*)(pair + ibase + (size_t)jbase * PD);
  f32x4 acc[8];
  #pragma unroll
  for (int k = 0; k < 8; ++k)
    acc[k] = __builtin_nontemporal_load(&pp[k * 16 + pl]);
  __builtin_amdgcn_sched_barrier(0);

  // 2) async staging from L2-resident sources
  {
    const float* tb = tg + (size_t)i * (DM * PD) + w * 512 + lane * 4;
    float* tl = t_lds + w * 512;
    g2l16(tb, tl);
    g2l16(tb + 256, tl + 256);
  }
  {
    // wave w stages s rows c = w*8 .. w*8+8; one g2l covers 2 rows (512B each)
    #pragma unroll
    for (int q = 0; q < 4; ++q) {
      const float* sb = sT + (size_t)(w * 8 + q * 2 + (lane >> 5)) * LSEQ
                        + jt + (lane & 31) * 4;
      g2l16(sb, &s_lds[w * 8 + q * 2][0]);
    }
  }
  __syncthreads();

  // 3) bias into acc
  f32x4 b0 = ((const f32x4*)b2)[pl];
  #pragma unroll
  for (int k = 0; k < 8; ++k) acc[k] += b0;

  // 4) contraction over c: 3 LDS b128 reads + 8 fma4 per c
  const f32x4* t4 = (const f32x4*)t_lds;            // [c*16 + pl]
  const f32x4* s4 = (const f32x4*)&s_lds[0][0];     // [c*32 + sbase {,+1}]
  int sbase = w * 8 + g * 2;
  #pragma unroll 8
  for (int c = 0; c < DM; ++c) {
    f32x4 tv = t4[c * 16 + pl];
    f32x4 sA = s4[c * 32 + sbase];
    f32x4 sB = s4[c * 32 + sbase + 1];
    fma4(acc[0], sA.x, tv);
    fma4(acc[1], sA.y, tv);
    fma4(acc[2], sA.z, tv);
    fma4(acc[3], sA.w, tv);
    fma4(acc[4], sB.x, tv);
    fma4(acc[5], sB.y, tv);
    fma4(acc[6], sB.z, tv);
    fma4(acc[7], sB.w, tv);
  }

  // 5) stores: same contiguous mapping
  f32x4* po = (f32x4*)(out + ibase + (size_t)jbase * PD);
  #pragma unroll
  for (int k = 0; k < 8; ++k)
    __builtin_nontemporal_store(acc[k], &po[k * 16 + pl]);
}

// Fallback (ws too small for t): single-tile kernel computing t in-block.
__global__ __launch_bounds__(256) void k_main_fb(const float* __restrict__ sT,
    const float* __restrict__ W2, const float* __restrict__ b2,
    const float* __restrict__ pair, float* __restrict__ out) {
  __shared__ float t_lds[DM][PD];
  __shared__ float s_lds[DM][128];
  __shared__ float sish[DM];
  int tid = threadIdx.x;
  int bid = ((blockIdx.x & 7) << 10) + (blockIdx.x >> 3);
  int i = bid >> 3;
  int jt = (bid & 7) * 128;
  int pl = tid & 7, jg = tid >> 3;
  if (tid < DM) sish[tid] = sT[tid * LSEQ + i];
  __syncthreads();
  {
    int p = tid & 63, c0 = tid >> 6;
    #pragma unroll
    for (int k = 0; k < 8; ++k) {
      int c = c0 * 8 + k;
      float acc = 0.f;
      #pragma unroll
      for (int d = 0; d < DM; ++d)
        acc = fmaf(sish[d], W2[(c * DM + d) * PD + p], acc);
      t_lds[c][p] = acc;
    }
  }
  #pragma unroll
  for (int k = 0; k < 2; ++k) {
    int idx = k * 256 + tid;
    int c = idx >> 5, j4 = idx & 31;
    ((f32x4*)&s_lds[0][0])[idx] =
        ((const f32x4*)(sT + (size_t)c * LSEQ + jt))[j4];
  }
  __syncthreads();
  size_t rowbase = (size_t)i * (LSEQ * PD) + (size_t)(jt + jg * 4) * PD;
  const f32x4* pp = (const f32x4*)(pair + rowbase);
  f32x4 acc0[4], acc1[4];
  #pragma unroll
  for (int jj = 0; jj < 4; ++jj) {
    acc0[jj] = pp[jj * 16 + pl];
    acc1[jj] = pp[jj * 16 + 8 + pl];
  }
  const f32x4* t4 = (const f32x4*)&t_lds[0][0];
  const f32x4* s4 = (const f32x4*)&s_lds[0][0];
  #pragma unroll 8
  for (int c = 0; c < DM; ++c) {
    f32x4 t0 = t4[c * 16 + pl];
    f32x4 t1 = t4[c * 16 + 8 + pl];
    f32x4 sA = s4[c * 32 + jg];
    fma4(acc0[0], sA.x, t0); fma4(acc1[0], sA.x, t1);
    fma4(acc0[1], sA.y, t0); fma4(acc1[1], sA.y, t1);
    fma4(acc0[2], sA.z, t0); fma4(acc1[2], sA.z, t1);
    fma4(acc0[3], sA.w, t0); fma4(acc1[3], sA.w, t1);
  }
  const f32x4* b24 = (const f32x4*)b2;
  f32x4 b0 = b24[pl], b1v = b24[8 + pl];
  f32x4* po = (f32x4*)(out + rowbase);
  #pragma unroll
  for (int jj = 0; jj < 4; ++jj) {
    po[jj * 16 + pl] = acc0[jj] + b0;
    po[jj * 16 + 8 + pl] = acc1[jj] + b1v;
  }
}

extern "C" void kernel_launch(void* const* d_in, const int* in_sizes, int n_in,
                              void* d_out, int out_size, void* d_ws, size_t ws_size,
                              hipStream_t stream) {
  const float* seq  = (const float*)d_in[0];
  const float* pair = (const float*)d_in[1];
  const float* W1   = (const float*)d_in[2];
  const float* b1   = (const float*)d_in[3];
  const float* W2   = (const float*)d_in[4];
  const float* b2   = (const float*)d_in[5];
  float* out = (float*)d_out;
  float* ws  = (float*)d_ws;

  float* sT = ws;                       // 32*1024 floats (128 KB)
  float* t  = ws + DM * LSEQ;           // 1024*32*64 floats (8 MB)
  size_t need = (size_t)(DM * LSEQ + (size_t)LSEQ * DM * PD) * sizeof(float);

  if (ws_size >= need) {
    k_prep<true><<<LSEQ / 4, 256, 0, stream>>>(seq, W1, b1, W2, sT, t);
    k_main<<<LSEQ * 8, 256, 0, stream>>>(sT, t, b2, pair, out);
  } else {
    k_prep<false><<<LSEQ / 4, 256, 0, stream>>>(seq, W1, b1, W2, sT, nullptr);
    k_main_fb<<<LSEQ * 8, 256, 0, stream>>>(sT, W2, b2, pair, out);
  }
}

// Round 11
// 134.503 us; speedup vs baseline: 1.4520x; 1.4520x over previous
//
#include <hip/hip_runtime.h>

#define LSEQ 1024
#define INDIM 256
#define DM 32
#define PD 64
#define JT 128
#define IC 4

typedef float f32x4 __attribute__((ext_vector_type(4)));

__device__ __forceinline__ void fma4(f32x4& a, float s, const f32x4& t) {
  a.x = fmaf(s, t.x, a.x); a.y = fmaf(s, t.y, a.y);
  a.z = fmaf(s, t.z, a.z); a.w = fmaf(s, t.w, a.w);
}

__device__ __forceinline__ void g2l16(const float* g, float* l) {
  __builtin_amdgcn_global_load_lds(
      (__attribute__((address_space(1))) void*)g,
      (__attribute__((address_space(3))) void*)l, 16, 0, 0);
}

// Fused prep, 4 rows per block (unchanged):
template<bool WRT>
__global__ __launch_bounds__(256) void k_prep(const float* __restrict__ seq,
    const float* __restrict__ W1, const float* __restrict__ b1,
    const float* __restrict__ W2, float* __restrict__ sT,
    float* __restrict__ t_out) {
  int i0 = blockIdx.x * 4;
  int tid = threadIdx.x;
  __shared__ float srow[4][INDIM];
  __shared__ float part[4][2][DM];
  __shared__ float si[4][DM];
  ((f32x4*)&srow[0][0])[tid] =
      ((const f32x4*)(seq + (size_t)i0 * INDIM))[tid];
  __syncthreads();
  {
    int c = tid & 31, dseg = (tid >> 5) & 1, il = tid >> 6;
    float a = 0.f;
    #pragma unroll 16
    for (int d = 0; d < 128; ++d)
      a = fmaf(srow[il][dseg * 128 + d], W1[(dseg * 128 + d) * DM + c], a);
    part[il][dseg][c] = a;
  }
  __syncthreads();
  if (tid < 128) {
    int il = tid >> 5, c = tid & 31;
    float a = b1[c] + part[il][0][c] + part[il][1][c];
    si[il][c] = a;
    sT[c * LSEQ + i0 + il] = a;
  }
  __syncthreads();
  if constexpr (WRT) {
    int p = tid & 63, c0 = tid >> 6;
    #pragma unroll
    for (int k = 0; k < 8; ++k) {
      int c = c0 * 8 + k;
      float a0 = 0.f, a1 = 0.f, a2 = 0.f, a3 = 0.f;
      #pragma unroll
      for (int d = 0; d < DM; ++d) {
        float w = W2[(c * DM + d) * PD + p];
        a0 = fmaf(si[0][d], w, a0);
        a1 = fmaf(si[1][d], w, a1);
        a2 = fmaf(si[2][d], w, a2);
        a3 = fmaf(si[3][d], w, a3);
      }
      t_out[((size_t)(i0 + 0) * DM + c) * PD + p] = a0;
      t_out[((size_t)(i0 + 1) * DM + c) * PD + p] = a1;
      t_out[((size_t)(i0 + 2) * DM + c) * PD + p] = a2;
      t_out[((size_t)(i0 + 3) * DM + c) * PD + p] = a3;
    }
  }
}

// i-loop main: block = (j-tile of 128) x (IC=4 consecutive i).
// s-tile staged ONCE; t[i] double-buffered, prefetched BEFORE the pair loads
// so any pair consumption (in-order vmcnt pop) implies t landed -> in-loop
// barriers are plain s_barrier, never draining the pair/out streams.
// Inner loop/thread map = proven champion (R4): pl=tid&7 (two p-quads),
// jg=tid>>3 (4 j rows), acc loaded from pair.
__global__ __launch_bounds__(256) void k_main(const float* __restrict__ sT,
    const float* __restrict__ tg, const float* __restrict__ b2,
    const float* __restrict__ pair, float* __restrict__ out) {
  __shared__ float s_lds[DM][JT];       // 16 KB
  __shared__ float t_lds[2][DM * PD];   // 16 KB -> 32 KB total, 5 blocks/CU
  int tid = threadIdx.x;
  int lane = tid & 63, w = tid >> 6;
  int b = blockIdx.x;
  // 2048 blocks: XCD k owns i-chunks [k*32,(k+1)*32); the 8 j-tiles of one
  // chunk are consecutive on that XCD -> t[i] L2-hit after first touch.
  int q = b >> 3;
  int jt = (q & 7) * JT;
  int i0 = ((b & 7) * 32 + (q >> 3)) * IC;
  int pl = tid & 7;     // p = pl*4..+3 and 32+pl*4..+3
  int jg = tid >> 3;    // j = jt + jg*4 + jj

  // prologue: stage s-tile (rows w*8..w*8+8) + t[i0] into buffer 0
  #pragma unroll
  for (int q4 = 0; q4 < 4; ++q4) {
    const float* sb = sT + (size_t)(w * 8 + q4 * 2 + (lane >> 5)) * LSEQ
                      + jt + (lane & 31) * 4;
    g2l16(sb, &s_lds[w * 8 + q4 * 2][0]);   // uniform dest; lanes 32-63 -> row+1
  }
  {
    const float* tb = tg + (size_t)i0 * (DM * PD) + w * 512 + lane * 4;
    g2l16(tb, &t_lds[0][0] + w * 512);
    g2l16(tb + 256, &t_lds[0][0] + w * 512 + 256);
  }
  asm volatile("s_waitcnt vmcnt(0)" ::: "memory");
  __builtin_amdgcn_s_barrier();
  __builtin_amdgcn_sched_barrier(0);

  const f32x4* b24 = (const f32x4*)b2;
  f32x4 b0 = b24[pl], b1v = b24[8 + pl];
  const f32x4* s4 = (const f32x4*)&s_lds[0][0];   // [c*32 + jg]

  #pragma unroll
  for (int ii = 0; ii < IC; ++ii) {
    const int cur = ii & 1;
    // a) prefetch t[i0+ii+1] into other buffer (issued BEFORE pair loads:
    //    older in the vmcnt queue, popped by any pair consumption below)
    if (ii < IC - 1) {
      const float* tb = tg + (size_t)(i0 + ii + 1) * (DM * PD) + w * 512 + lane * 4;
      g2l16(tb, &t_lds[cur ^ 1][0] + w * 512);
      g2l16(tb + 256, &t_lds[cur ^ 1][0] + w * 512 + 256);
    }
    __builtin_amdgcn_sched_barrier(0);

    // b) pair loads straight into accumulators
    size_t rowbase = (size_t)(i0 + ii) * (LSEQ * PD) + (size_t)(jt + jg * 4) * PD;
    const f32x4* pp = (const f32x4*)(pair + rowbase);
    f32x4 acc0[4], acc1[4];
    #pragma unroll
    for (int jj = 0; jj < 4; ++jj) {
      acc0[jj] = __builtin_nontemporal_load(&pp[jj * 16 + pl]);
      acc1[jj] = __builtin_nontemporal_load(&pp[jj * 16 + 8 + pl]);
    }
    __builtin_amdgcn_sched_barrier(0);

    // c) contraction over c (t from current buffer, s fixed)
    const f32x4* t4 = (const f32x4*)&t_lds[cur][0];
    #pragma unroll 8
    for (int c = 0; c < DM; ++c) {
      f32x4 t0 = t4[c * 16 + pl];
      f32x4 t1 = t4[c * 16 + 8 + pl];
      f32x4 sA = s4[c * 32 + jg];
      fma4(acc0[0], sA.x, t0); fma4(acc1[0], sA.x, t1);
      fma4(acc0[1], sA.y, t0); fma4(acc1[1], sA.y, t1);
      fma4(acc0[2], sA.z, t0); fma4(acc1[2], sA.z, t1);
      fma4(acc0[3], sA.w, t0); fma4(acc1[3], sA.w, t1);
    }

    // d) bias + stores
    f32x4* po = (f32x4*)(out + rowbase);
    #pragma unroll
    for (int jj = 0; jj < 4; ++jj) {
      __builtin_nontemporal_store(acc0[jj] + b0, &po[jj * 16 + pl]);
      __builtin_nontemporal_store(acc1[jj] + b1v, &po[jj * 16 + 8 + pl]);
    }

    // e) plain barrier: all waves done reading t_lds[cur] before next iter's
    //    prefetch overwrites it. No vmcnt drain (stores/loads keep flowing).
    if (ii < IC - 1) {
      __builtin_amdgcn_s_barrier();
      __builtin_amdgcn_sched_barrier(0);
    }
  }
}

// Fallback (ws too small for t): single-tile kernel computing t in-block.
__global__ __launch_bounds__(256) void k_main_fb(const float* __restrict__ sT,
    const float* __restrict__ W2, const float* __restrict__ b2,
    const float* __restrict__ pair, float* __restrict__ out) {
  __shared__ float t_lds[DM][PD];
  __shared__ float s_lds[DM][128];
  __shared__ float sish[DM];
  int tid = threadIdx.x;
  int bid = ((blockIdx.x & 7) << 10) + (blockIdx.x >> 3);
  int i = bid >> 3;
  int jt = (bid & 7) * 128;
  int pl = tid & 7, jg = tid >> 3;
  if (tid < DM) sish[tid] = sT[tid * LSEQ + i];
  __syncthreads();
  {
    int p = tid & 63, c0 = tid >> 6;
    #pragma unroll
    for (int k = 0; k < 8; ++k) {
      int c = c0 * 8 + k;
      float acc = 0.f;
      #pragma unroll
      for (int d = 0; d < DM; ++d)
        acc = fmaf(sish[d], W2[(c * DM + d) * PD + p], acc);
      t_lds[c][p] = acc;
    }
  }
  #pragma unroll
  for (int k = 0; k < 2; ++k) {
    int idx = k * 256 + tid;
    int c = idx >> 5, j4 = idx & 31;
    ((f32x4*)&s_lds[0][0])[idx] =
        ((const f32x4*)(sT + (size_t)c * LSEQ + jt))[j4];
  }
  __syncthreads();
  size_t rowbase = (size_t)i * (LSEQ * PD) + (size_t)(jt + jg * 4) * PD;
  const f32x4* pp = (const f32x4*)(pair + rowbase);
  f32x4 acc0[4], acc1[4];
  #pragma unroll
  for (int jj = 0; jj < 4; ++jj) {
    acc0[jj] = pp[jj * 16 + pl];
    acc1[jj] = pp[jj * 16 + 8 + pl];
  }
  const f32x4* t4 = (const f32x4*)&t_lds[0][0];
  const f32x4* s4 = (const f32x4*)&s_lds[0][0];
  #pragma unroll 8
  for (int c = 0; c < DM; ++c) {
    f32x4 t0 = t4[c * 16 + pl];
    f32x4 t1 = t4[c * 16 + 8 + pl];
    f32x4 sA = s4[c * 32 + jg];
    fma4(acc0[0], sA.x, t0); fma4(acc1[0], sA.x, t1);
    fma4(acc0[1], sA.y, t0); fma4(acc1[1], sA.y, t1);
    fma4(acc0[2], sA.z, t0); fma4(acc1[2], sA.z, t1);
    fma4(acc0[3], sA.w, t0); fma4(acc1[3], sA.w, t1);
  }
  const f32x4* b24 = (const f32x4*)b2;
  f32x4 b0 = b24[pl], b1v = b24[8 + pl];
  f32x4* po = (f32x4*)(out + rowbase);
  #pragma unroll
  for (int jj = 0; jj < 4; ++jj) {
    po[jj * 16 + pl] = acc0[jj] + b0;
    po[jj * 16 + 8 + pl] = acc1[jj] + b1v;
  }
}

extern "C" void kernel_launch(void* const* d_in, const int* in_sizes, int n_in,
                              void* d_out, int out_size, void* d_ws, size_t ws_size,
                              hipStream_t stream) {
  const float* seq  = (const float*)d_in[0];
  const float* pair = (const float*)d_in[1];
  const float* W1   = (const float*)d_in[2];
  const float* b1   = (const float*)d_in[3];
  const float* W2   = (const float*)d_in[4];
  const float* b2   = (const float*)d_in[5];
  float* out = (float*)d_out;
  float* ws  = (float*)d_ws;

  float* sT = ws;                       // 32*1024 floats (128 KB)
  float* t  = ws + DM * LSEQ;           // 1024*32*64 floats (8 MB)
  size_t need = (size_t)(DM * LSEQ + (size_t)LSEQ * DM * PD) * sizeof(float);

  if (ws_size >= need) {
    k_prep<true><<<LSEQ / 4, 256, 0, stream>>>(seq, W1, b1, W2, sT, t);
    k_main<<<(LSEQ / JT) * (LSEQ / IC), 256, 0, stream>>>(sT, t, b2, pair, out);
  } else {
    k_prep<false><<<LSEQ / 4, 256, 0, stream>>>(seq, W1, b1, W2, sT, nullptr);
    k_main_fb<<<LSEQ * 8, 256, 0, stream>>>(sT, W2, b2, pair, out);
  }
}

// Round 12
// 126.881 us; speedup vs baseline: 1.5392x; 1.0601x over previous
//
#include <hip/hip_runtime.h>
#include <stdint.h>

#define LSEQ 1024
#define INDIM 256
#define DM 32
#define PD 64
#define JT 256
#define NJT (LSEQ / JT)   // 4

typedef float f32x4 __attribute__((ext_vector_type(4)));

__device__ __forceinline__ void fma4(f32x4& a, float s, const f32x4& t) {
  a.x = fmaf(s, t.x, a.x); a.y = fmaf(s, t.y, a.y);
  a.z = fmaf(s, t.z, a.z); a.w = fmaf(s, t.w, a.w);
}

__device__ __forceinline__ void g2l16(const float* g, float* l) {
  __builtin_amdgcn_global_load_lds(
      (__attribute__((address_space(1))) void*)g,
      (__attribute__((address_space(3))) void*)l, 16, 0, 0);
}

// Fused prep, 4 rows per block (unchanged):
template<bool WRT>
__global__ __launch_bounds__(256) void k_prep(const float* __restrict__ seq,
    const float* __restrict__ W1, const float* __restrict__ b1,
    const float* __restrict__ W2, float* __restrict__ sT,
    float* __restrict__ t_out) {
  int i0 = blockIdx.x * 4;
  int tid = threadIdx.x;
  __shared__ float srow[4][INDIM];
  __shared__ float part[4][2][DM];
  __shared__ float si[4][DM];
  ((f32x4*)&srow[0][0])[tid] =
      ((const f32x4*)(seq + (size_t)i0 * INDIM))[tid];
  __syncthreads();
  {
    int c = tid & 31, dseg = (tid >> 5) & 1, il = tid >> 6;
    float a = 0.f;
    #pragma unroll 16
    for (int d = 0; d < 128; ++d)
      a = fmaf(srow[il][dseg * 128 + d], W1[(dseg * 128 + d) * DM + c], a);
    part[il][dseg][c] = a;
  }
  __syncthreads();
  if (tid < 128) {
    int il = tid >> 5, c = tid & 31;
    float a = b1[c] + part[il][0][c] + part[il][1][c];
    si[il][c] = a;
    sT[c * LSEQ + i0 + il] = a;
  }
  __syncthreads();
  if constexpr (WRT) {
    int p = tid & 63, c0 = tid >> 6;
    #pragma unroll
    for (int k = 0; k < 8; ++k) {
      int c = c0 * 8 + k;
      float a0 = 0.f, a1 = 0.f, a2 = 0.f, a3 = 0.f;
      #pragma unroll
      for (int d = 0; d < DM; ++d) {
        float w = W2[(c * DM + d) * PD + p];
        a0 = fmaf(si[0][d], w, a0);
        a1 = fmaf(si[1][d], w, a1);
        a2 = fmaf(si[2][d], w, a2);
        a3 = fmaf(si[3][d], w, a3);
      }
      t_out[((size_t)(i0 + 0) * DM + c) * PD + p] = a0;
      t_out[((size_t)(i0 + 1) * DM + c) * PD + p] = a1;
      t_out[((size_t)(i0 + 2) * DM + c) * PD + p] = a2;
      t_out[((size_t)(i0 + 3) * DM + c) * PD + p] = a3;
    }
  }
}

// R6 structure exactly; single change: out stores are PLAIN (write-back,
// L2-coalesced) while pair loads stay nontemporal. A/B vs R6 = 130.3 us.
template<bool TPRE>
__global__ __launch_bounds__(256) void k_main(const float* __restrict__ sT,
    const float* __restrict__ tg, const float* __restrict__ W2,
    const float* __restrict__ b2, const float* __restrict__ pair,
    float* __restrict__ out) {
  __shared__ float t_lds[DM][PD];    // 8 KB
  __shared__ float s_lds[DM][JT];    // 32 KB
  int tid = threadIdx.x;
  // XCD-chunked bijective swizzle (4096 % 8 == 0)
  int bid = ((blockIdx.x & 7) << 9) + (blockIdx.x >> 3);
  int i = bid >> 2;
  int jt = (bid & (NJT - 1)) * JT;
  int pl = tid & 7;           // p = pl*4..+3 and 32+pl*4..+3
  int jg = tid >> 3;          // 0..31: j = jt + jg*8 + jj
  int lane = tid & 63, w = tid >> 6;

  // 1) async staging from L2-resident sources
  if constexpr (TPRE) {
    const float* tb = tg + (size_t)i * (DM * PD) + w * 512 + lane * 4;
    float* tl = &t_lds[0][0] + w * 512;
    g2l16(tb, tl);
    g2l16(tb + 256, tl + 256);
  }
  {
    const float* sb = sT + (size_t)(w * 8) * LSEQ + jt + lane * 4;
    float* sl = &s_lds[w * 8][0];
    #pragma unroll
    for (int q = 0; q < 8; ++q)
      g2l16(sb + q * LSEQ, sl + q * JT);
  }
  if constexpr (!TPRE) {
    __shared__ float sish[DM];
    if (tid < DM) sish[tid] = sT[tid * LSEQ + i];
    __syncthreads();
    int p = tid & 63, c0 = tid >> 6;
    #pragma unroll
    for (int k = 0; k < 8; ++k) {
      int c = c0 * 8 + k;
      float acc = 0.f;
      #pragma unroll
      for (int d = 0; d < DM; ++d)
        acc = fmaf(sish[d], W2[(c * DM + d) * PD + p], acc);
      t_lds[c][p] = acc;
    }
  }
  __syncthreads();   // drains g2l staging only (L2 sources, fast)

  // 2) NOW issue pair loads (nontemporal: keep L2 clean for t/sT)
  size_t rowbase = (size_t)i * (LSEQ * PD) + (size_t)(jt + jg * 8) * PD;
  const f32x4* pp = (const f32x4*)(pair + rowbase);
  f32x4 pf0[8], pf1[8];
  #pragma unroll
  for (int jj = 0; jj < 8; ++jj) {
    pf0[jj] = __builtin_nontemporal_load(&pp[jj * 16 + pl]);
    pf1[jj] = __builtin_nontemporal_load(&pp[jj * 16 + 8 + pl]);
  }
  __builtin_amdgcn_sched_barrier(0);   // pin load issue point here

  // 3) contraction into fresh sum regs (independent of the in-flight loads)
  f32x4 s0[8], s1[8];
  #pragma unroll
  for (int jj = 0; jj < 8; ++jj) { s0[jj] = (f32x4)(0.f); s1[jj] = (f32x4)(0.f); }
  const f32x4* t4 = (const f32x4*)&t_lds[0][0];  // [c*16 + pidx]
  const f32x4* s4 = (const f32x4*)&s_lds[0][0];  // [c*64 + jg*2 + {0,1}]
  #pragma unroll 8
  for (int c = 0; c < DM; ++c) {
    f32x4 t0 = t4[c * 16 + pl];
    f32x4 t1 = t4[c * 16 + 8 + pl];
    f32x4 sA = s4[c * 64 + jg * 2];
    f32x4 sB = s4[c * 64 + jg * 2 + 1];
    fma4(s0[0], sA.x, t0); fma4(s1[0], sA.x, t1);
    fma4(s0[1], sA.y, t0); fma4(s1[1], sA.y, t1);
    fma4(s0[2], sA.z, t0); fma4(s1[2], sA.z, t1);
    fma4(s0[3], sA.w, t0); fma4(s1[3], sA.w, t1);
    fma4(s0[4], sB.x, t0); fma4(s1[4], sB.x, t1);
    fma4(s0[5], sB.y, t0); fma4(s1[5], sB.y, t1);
    fma4(s0[6], sB.z, t0); fma4(s1[6], sB.z, t1);
    fma4(s0[7], sB.w, t0); fma4(s1[7], sB.w, t1);
  }

  // 4) epilogue: PLAIN stores (L2 write-back coalescing; no nt write path)
  const f32x4* b24 = (const f32x4*)b2;
  f32x4 b0 = b24[pl], b1v = b24[8 + pl];
  f32x4* po = (f32x4*)(out + rowbase);
  #pragma unroll
  for (int jj = 0; jj < 8; ++jj) {
    po[jj * 16 + pl] = s0[jj] + pf0[jj] + b0;
    po[jj * 16 + 8 + pl] = s1[jj] + pf1[jj] + b1v;
  }
}

extern "C" void kernel_launch(void* const* d_in, const int* in_sizes, int n_in,
                              void* d_out, int out_size, void* d_ws, size_t ws_size,
                              hipStream_t stream) {
  const float* seq  = (const float*)d_in[0];
  const float* pair = (const float*)d_in[1];
  const float* W1   = (const float*)d_in[2];
  const float* b1   = (const float*)d_in[3];
  const float* W2   = (const float*)d_in[4];
  const float* b2   = (const float*)d_in[5];
  float* out = (float*)d_out;
  float* ws  = (float*)d_ws;

  float* sT = ws;                       // 32*1024 floats (128 KB)
  float* t  = ws + DM * LSEQ;           // 1024*32*64 floats (8 MB)
  size_t need = (size_t)(DM * LSEQ + (size_t)LSEQ * DM * PD) * sizeof(float);

  if (ws_size >= need) {
    k_prep<true><<<LSEQ / 4, 256, 0, stream>>>(seq, W1, b1, W2, sT, t);
    k_main<true><<<LSEQ * NJT, 256, 0, stream>>>(sT, t, W2, b2, pair, out);
  } else {
    k_prep<false><<<LSEQ / 4, 256, 0, stream>>>(seq, W1, b1, W2, sT, nullptr);
    k_main<false><<<LSEQ * NJT, 256, 0, stream>>>(sT, nullptr, W2, b2, pair, out);
  }
}